// Round 5
// baseline (432.996 us; speedup 1.0000x reference)
//
#include <hip/hip_runtime.h>
#include <cstdint>
#include <cmath>

#define N_HEADS 16
#define I_DIM 128
#define H_DIM 128
#define B_SZ 16
#define T_SZ 512
#define G3 384           // 3*H
#define BT (B_SZ * T_SZ) // 8192
#define LDW 136          // padded LDS row stride in bf16 (128+8), keeps 16B align
#define OUT_HN_OFFSET ((size_t)B_SZ * T_SZ * (N_HEADS * H_DIM)) // 16777216
#define CHUNK 8
#define NCHUNK (T_SZ / CHUNK) // 64

typedef __attribute__((ext_vector_type(8))) short bf16x8;
typedef __attribute__((ext_vector_type(4))) float f32x4;

static __device__ __forceinline__ unsigned short f2bf(float f) {
  unsigned int u = __float_as_uint(f);
  unsigned int r = (u + 0x7FFFu + ((u >> 16) & 1u)) >> 16; // RNE
  return (unsigned short)r;
}
static __device__ __forceinline__ float bf2f(unsigned short s) {
  return __uint_as_float((unsigned int)s << 16);
}
static __device__ __forceinline__ uint2 pack4(float4 v) {
  uint2 p;
  p.x = (unsigned int)f2bf(v.x) | ((unsigned int)f2bf(v.y) << 16);
  p.y = (unsigned int)f2bf(v.z) | ((unsigned int)f2bf(v.w) << 16);
  return p;
}
static __device__ __forceinline__ bf16x8 pack8(float4 a, float4 b) {
  union { uint2 u[2]; bf16x8 v; } r;
  r.u[0] = pack4(a);
  r.u[1] = pack4(b);
  return r.v;
}

// ---------------------------------------------------------------------------
// Kernel A v4: register-resident W, 2 WGs/CU.
// R4 post-mortem: A stayed ~132us after store-coalescing -> not store-bound;
// it is occupancy/latency-bound (1 WG/CU, 104KB W-LDS, DS-heavy inner loop,
// zero TLP). Fix: wave w owns gate-column pairs {2w,2w+1}; its W fragments
// (3gb x 2j x 4kt = 96 VGPR) are packed ONCE into registers. W-LDS is gone
// -> LDS = 17KB (X tile only) -> __launch_bounds__(256,2) gives 2 WGs/CU
// whose phases overlap. DS reads/tile/wave drop 108 -> 48 b128.
// Grid 32x16, 4 tiles of 64 bt per WG. Per-element arithmetic identical.
// ---------------------------------------------------------------------------
__global__ __launch_bounds__(256, 2) void gates_x_mfma(
    const float* __restrict__ x, const float* __restrict__ w_ih,
    const float* __restrict__ b_ih, unsigned short* __restrict__ gates) {
  const int n = blockIdx.z;
  const int grp = blockIdx.x; // 0..31, 4 tiles of 64 bt-rows each
  const int tid = threadIdx.x;
  const int wave = tid >> 6;
  const int lane = tid & 63;
  const int m16 = lane & 15;
  const int quad = lane >> 4;

  __shared__ __align__(16) unsigned short Xs[64 * LDW]; // 17,408 B

  const int xrow = tid >> 2;
  const int xq = tid & 3;

  // First X tile prefetch (overlaps W packing).
  float4 xf[8];
  {
    const float4* xg =
        (const float4*)(x + (size_t)(grp * 256 + xrow) * 2048 + n * I_DIM) +
        xq * 8;
#pragma unroll
    for (int i = 0; i < 8; ++i) xf[i] = xg[i];
  }

  // Register-resident W_ih fragments for this wave's column pair.
  bf16x8 wfr[3][2][4];
  float bias[3][2];
#pragma unroll
  for (int gb = 0; gb < 3; ++gb) {
#pragma unroll
    for (int jj = 0; jj < 2; ++jj) {
      const int g = gb * 128 + (2 * wave + jj) * 16 + m16;
      const float4* wr = (const float4*)(w_ih + ((size_t)n * G3 + g) * I_DIM);
#pragma unroll
      for (int kt = 0; kt < 4; ++kt)
        wfr[gb][jj][kt] = pack8(wr[kt * 8 + quad * 2], wr[kt * 8 + quad * 2 + 1]);
      bias[gb][jj] = b_ih[n * G3 + g];
    }
  }

  for (int tile = 0; tile < 4; ++tile) {
    const int bt0 = grp * 256 + tile * 64;

    __syncthreads(); // prev tile's Xs reads done (tile 0: trivial)
#pragma unroll
    for (int i = 0; i < 8; ++i)
      *(uint2*)&Xs[xrow * LDW + xq * 32 + i * 4] = pack4(xf[i]);
    __syncthreads(); // Xs visible

    if (tile < 3) {
      const float4* xg =
          (const float4*)(x + (size_t)(bt0 + 64 + xrow) * 2048 + n * I_DIM) +
          xq * 8;
#pragma unroll
      for (int i = 0; i < 8; ++i) xf[i] = xg[i];
    }

#pragma unroll
    for (int gb = 0; gb < 3; ++gb) {
      f32x4 acc[4][2];
#pragma unroll
      for (int m = 0; m < 4; ++m)
#pragma unroll
        for (int jj = 0; jj < 2; ++jj) acc[m][jj] = (f32x4){0.f, 0.f, 0.f, 0.f};

#pragma unroll
      for (int kt = 0; kt < 4; ++kt) {
        bf16x8 af[4];
#pragma unroll
        for (int m = 0; m < 4; ++m)
          af[m] = *(const bf16x8*)&Xs[(m * 16 + m16) * LDW + kt * 32 + quad * 8];
#pragma unroll
        for (int m = 0; m < 4; ++m)
#pragma unroll
          for (int jj = 0; jj < 2; ++jj)
            acc[m][jj] = __builtin_amdgcn_mfma_f32_16x16x32_bf16(
                af[m], wfr[gb][jj][kt], acc[m][jj], 0, 0, 0);
      }

      // Epilogue: packed uint2 store (4 consecutive bt, same g).
#pragma unroll
      for (int m = 0; m < 4; ++m) {
#pragma unroll
        for (int jj = 0; jj < 2; ++jj) {
          const int g = gb * 128 + (2 * wave + jj) * 16 + m16;
          float4 v;
          v.x = acc[m][jj][0] + bias[gb][jj];
          v.y = acc[m][jj][1] + bias[gb][jj];
          v.z = acc[m][jj][2] + bias[gb][jj];
          v.w = acc[m][jj][3] + bias[gb][jj];
          const int bt = bt0 + m * 16 + quad * 4;
          *(uint2*)&gates[((size_t)n * G3 + g) * BT + bt] = pack4(v);
        }
      }
    }
  }
}

// ---------------------------------------------------------------------------
// Kernel B v6: 8-wave MFMA scan (512 thr). One WG per (b,n).
// R4 post-mortem: at 4 waves/CU (1/SIMD) the step is ISSUE/latency bound —
// every MFMA, DS op and the serial sigmoid/tanh chain issue from one wave
// with nothing to interleave (Occupancy 11.5%, MfmaUtil 29% = single-wave
// issue rate). Fix: 8 waves, wave w owns colblocks {w, 8+w, 16+w} (r,z,n for
// elems w*16..w*16+15) -> per-wave work halves (12 MFMA, 4 h-frag reads),
// 2 waves/SIMD interleave. Update lanes = quad 0 (elem = w*16+m16); r/z/n
// still consumed in-lane from acc regs. Chunked gates staging, h dbuf, one
// barrier/step, batched out stores — all as v5. Per-element math identical.
// ---------------------------------------------------------------------------
__global__ __launch_bounds__(512, 1) void gru_scan_kernel(
    const float* __restrict__ h0, const float* __restrict__ w_hh,
    const float* __restrict__ b_hh, const unsigned short* __restrict__ gates,
    float* __restrict__ out) {
  const int b = blockIdx.x >> 4;
  const int n = blockIdx.x & 15;
  const int tid = threadIdx.x;
  const int wave = tid >> 6;
  const int lane = tid & 63;
  const int m16 = lane & 15;
  const int quad = lane >> 4;

  __shared__ __align__(16) unsigned short h2[2][2][H_DIM];      // [buf][hi|lo]
  __shared__ __align__(16) unsigned short gbuf[2][CHUNK * 512]; // [s][e][4]

  // Register-resident W_hh bf16 B-fragments (verified layout).
  // Wave w colblocks: {w, 8+w, 16+w} -> r/z/n rows for elems w*16+m16.
  bf16x8 wf[3][4];
  {
    const int cbs[3] = {wave, 8 + wave, 16 + wave};
#pragma unroll
    for (int j = 0; j < 3; ++j) {
      const int g = cbs[j] * 16 + m16;
      const float4* wr = (const float4*)(w_hh + ((size_t)n * G3 + g) * H_DIM);
#pragma unroll
      for (int kt = 0; kt < 4; ++kt)
        wf[j][kt] = pack8(wr[kt * 8 + quad * 2], wr[kt * 8 + quad * 2 + 1]);
    }
  }

  const bool upd = (quad == 0);        // 128 updating lanes total
  const int elem = wave * 16 + m16;    // h element owned (if upd)

  float bh_r = 0.f, bh_z = 0.f, bh_n = 0.f, h_old = 0.f;
  if (upd) {
    bh_r = b_hh[n * G3 + elem];
    bh_z = b_hh[n * G3 + elem + 128];
    bh_n = b_hh[n * G3 + elem + 256];
    h_old = h0[(size_t)b * 2048 + n * H_DIM + elem];
    const unsigned short hh = f2bf(h_old);
    h2[0][0][elem] = hh;
    h2[0][1][elem] = f2bf(h_old - bf2f(hh));
  }

  // Gates rows: thread tid (<384) owns row g=tid at [(n*G3+g)*BT + b*512 + t].
  const size_t grow = ((size_t)n * G3 + tid) * BT + (size_t)b * T_SZ;

  // Scatter one row's 8-step uint4 into gbuf layout [s][e][{r,z,n,pad}].
  auto scatter = [&](unsigned short* buf, int g, uint4 v) {
    unsigned short* d = buf + (g & 127) * 4 + (g >> 7);
    d[0]    = (unsigned short)v.x;
    d[512]  = (unsigned short)(v.x >> 16);
    d[1024] = (unsigned short)v.y;
    d[1536] = (unsigned short)(v.y >> 16);
    d[2048] = (unsigned short)v.z;
    d[2560] = (unsigned short)(v.z >> 16);
    d[3072] = (unsigned short)v.w;
    d[3584] = (unsigned short)(v.w >> 16);
  };

  // Prologue: stage chunk 0.
  uint4 pfA = {0, 0, 0, 0};
  if (tid < G3) {
    pfA = *(const uint4*)(gates + grow);
    scatter(gbuf[0], tid, pfA);
  }
  __syncthreads();

  float* out_base = out + (size_t)b * T_SZ * 2048 + n * H_DIM;
  float oreg[CHUNK];

  for (int c = 0; c < NCHUNK; ++c) {
    const int gb = c & 1;

    // Issue next chunk's global loads (16B/row); retire over ~8 steps.
    if (c + 1 < NCHUNK && tid < G3)
      pfA = *(const uint4*)(gates + grow + (size_t)(c + 1) * CHUNK);

#pragma unroll
    for (int s = 0; s < CHUNK; ++s) {
      const int rb = s & 1; // chunk length even -> parity restarts at 0
      const int wb = rb ^ 1;

      // gates_x: ONE b64 read -> {r, z, n, pad}; unpack = 3 shifts.
      uint2 gxu = {0u, 0u};
      if (upd) gxu = *(const uint2*)&gbuf[gb][s * 512 + elem * 4];
      const float gxr = __uint_as_float(gxu.x << 16);
      const float gxz = __uint_as_float(gxu.x & 0xffff0000u);
      const float gxn = __uint_as_float(gxu.y << 16);

      // h A-fragments (hi for even m16 rows, lo for odd).
      const unsigned short* hsrc = &h2[rb][m16 & 1][0];
      const bf16x8 av0 = *(const bf16x8*)&hsrc[0 * 32 + quad * 8];
      const bf16x8 av1 = *(const bf16x8*)&hsrc[1 * 32 + quad * 8];
      const bf16x8 av2 = *(const bf16x8*)&hsrc[2 * 32 + quad * 8];
      const bf16x8 av3 = *(const bf16x8*)&hsrc[3 * 32 + quad * 8];

      f32x4 a0 = {0.f, 0.f, 0.f, 0.f};
      f32x4 a1 = {0.f, 0.f, 0.f, 0.f};
      f32x4 a2 = {0.f, 0.f, 0.f, 0.f};
      a0 = __builtin_amdgcn_mfma_f32_16x16x32_bf16(av0, wf[0][0], a0, 0, 0, 0);
      a1 = __builtin_amdgcn_mfma_f32_16x16x32_bf16(av0, wf[1][0], a1, 0, 0, 0);
      a2 = __builtin_amdgcn_mfma_f32_16x16x32_bf16(av0, wf[2][0], a2, 0, 0, 0);
      a0 = __builtin_amdgcn_mfma_f32_16x16x32_bf16(av1, wf[0][1], a0, 0, 0, 0);
      a1 = __builtin_amdgcn_mfma_f32_16x16x32_bf16(av1, wf[1][1], a1, 0, 0, 0);
      a2 = __builtin_amdgcn_mfma_f32_16x16x32_bf16(av1, wf[2][1], a2, 0, 0, 0);
      a0 = __builtin_amdgcn_mfma_f32_16x16x32_bf16(av2, wf[0][2], a0, 0, 0, 0);
      a1 = __builtin_amdgcn_mfma_f32_16x16x32_bf16(av2, wf[1][2], a1, 0, 0, 0);
      a2 = __builtin_amdgcn_mfma_f32_16x16x32_bf16(av2, wf[2][2], a2, 0, 0, 0);
      a0 = __builtin_amdgcn_mfma_f32_16x16x32_bf16(av3, wf[0][3], a0, 0, 0, 0);
      a1 = __builtin_amdgcn_mfma_f32_16x16x32_bf16(av3, wf[1][3], a1, 0, 0, 0);
      a2 = __builtin_amdgcn_mfma_f32_16x16x32_bf16(av3, wf[2][3], a2, 0, 0, 0);

      if (upd) {
        // D[0] = W.h_hi, D[1] = W.h_lo (quad 0 rows 0,1).
        const float ghr = a0[0] + a0[1] + bh_r;
        const float ghz = a1[0] + a1[1] + bh_z;
        const float ghn = a2[0] + a2[1] + bh_n;
        const float r = 1.f / (1.f + __expf(-(gxr + ghr)));
        const float z = 1.f / (1.f + __expf(-(gxz + ghz)));
        const float targ = gxn + r * ghn;
        const float rt = 1.f / (1.f + __expf(-2.f * targ)); // sigmoid(2x)
        const float nn = 2.f * rt - 1.f;                    // tanh(targ)
        const float hn = (1.f - z) * nn + z * h_old;
        const unsigned short hh = f2bf(hn);
        h2[wb][0][elem] = hh;
        h2[wb][1][elem] = f2bf(hn - bf2f(hh));
        h_old = hn;
        oreg[s] = hn;
      }

      // Stage next chunk into the other gbuf before the last step-barrier.
      if (s == CHUNK - 1 && c + 1 < NCHUNK && tid < G3)
        scatter(gbuf[gb ^ 1], tid, pfA);
      __syncthreads();
    }

    // Batched out stores (retire under next chunk).
    if (upd) {
#pragma unroll
      for (int s = 0; s < CHUNK; ++s)
        out_base[(size_t)(c * CHUNK + s) * 2048 + elem] = oreg[s];
    }
  }

  if (upd) {
    out[OUT_HN_OFFSET + (size_t)b * 2048 + n * H_DIM + elem] = h_old;
  }
}

extern "C" void kernel_launch(void* const* d_in, const int* in_sizes, int n_in,
                              void* d_out, int out_size, void* d_ws,
                              size_t ws_size, hipStream_t stream) {
  const float* x    = (const float*)d_in[0]; // [B, T, N*I]
  const float* h0   = (const float*)d_in[1]; // [1, B, N*H]
  const float* w_ih = (const float*)d_in[2]; // [N, 3H, I]
  const float* w_hh = (const float*)d_in[3]; // [N, 3H, H]
  const float* b_ih = (const float*)d_in[4]; // [N, 3H]
  const float* b_hh = (const float*)d_in[5]; // [N, 3H]
  float* out = (float*)d_out;
  unsigned short* gates = (unsigned short*)d_ws; // [N][G3][BT] bf16 = 96 MB

  dim3 gridA(32, 1, N_HEADS); // 512 WGs, 2/CU
  gates_x_mfma<<<gridA, 256, 0, stream>>>(x, w_ih, b_ih, gates);
  gru_scan_kernel<<<256, 512, 0, stream>>>(h0, w_hh, b_hh, gates, out);
}